// Round 14
// baseline (119.782 us; speedup 1.0000x reference)
//
#include <hip/hip_runtime.h>

#define BB 16
#define TT 30
#define NSEL 5
#define NCLS 10

typedef __attribute__((ext_vector_type(8))) short short8_t;
typedef __attribute__((ext_vector_type(4))) float f32x4;

__device__ inline unsigned short f2bf(float x) {
    unsigned int u = __float_as_uint(x);
    unsigned int r = u + 0x7FFFu + ((u >> 16) & 1u);
    return (unsigned short)(r >> 16);
}

// ---------------- prep_all: blocks 0..767 skim resize (scalar, 1 thr/px for occupancy);
//                  blocks 768..1055 weight pack + zeroing
__global__ __launch_bounds__(256) void prep_all(const float* __restrict__ ff64,
                                                const float* __restrict__ w2,
                                                const float* __restrict__ w1,
                                                float* __restrict__ skim_res,
                                                unsigned short* __restrict__ wpk,
                                                unsigned short* __restrict__ wpk1,
                                                float* __restrict__ gsum,
                                                float* __restrict__ gsum2) {
    int bid = blockIdx.x;
    int t = threadIdx.x;
    if (bid < 768) {
        // 196608 scalar outputs; 62-tap triangle resize, identical summation order
        // to the float4 version (bit-identical results), 4x the TLP.
        int gid = bid * 256 + t;
        int ox = gid & 63;
        int oy = (gid >> 6) & 63;
        int bc = gid >> 12;
        int c = bc % 3, b = bc / 3;
        float sample = 30.f * (float)oy + 14.5f;
        int jlo = max(0, 30 * oy - 16);
        int jhi = min(TT * 64 - 1, 30 * oy + 45);
        float acc = 0.f, ws = 0.f;
        for (int j = jlo; j <= jhi; ++j) {
            float w = fmaxf(0.f, 1.f - fabsf(sample - (float)j) * (1.f / 30.f));
            int tt = j >> 6, y = j & 63;
            acc += w * ff64[(((b * TT + tt) * 3 + c) << 12) + (y << 6) + ox];
            ws += w;
        }
        skim_res[(((b * 3 + c) << 6) + oy) * 64 + ox] = acc / ws;
    } else {
        int i = (bid - 768) * 256 + t;
        if (i < BB * 128) gsum[i] = 0.f;
        if (i < BB * 64) gsum2[i] = 0.f;
        if (i < 4 * 64 * 8) {
            int j = i & 7;
            int lane = (i >> 3) & 63;
            int af = i >> 9;
            int oc = af * 16 + (lane & 15);
            int k = ((lane >> 4) << 3) + j;
            wpk1[i] = (k < 27) ? f2bf(w1[oc * 27 + k]) : (unsigned short)0;
        }
        if (i < 9 * 2 * 8 * 64 * 8) {
            int j = i & 7;
            int lane = (i >> 3) & 63;
            int af = (i >> 9) & 7;
            int h = (i >> 12) & 1;
            int tap = i >> 13;
            int oc = af * 16 + (lane & 15);
            int ic = h * 32 + ((lane >> 4) << 3) + j;
            int ky = tap / 3, kx = tap % 3;
            wpk[i] = f2bf(w2[((size_t)(oc * 64 + ic)) * 9 + ky * 3 + kx]);
        }
    }
}

// ---------------- skim conv1 tiled fp32 (exact): [16,3,64,64] -> [16,32,32,32]
__global__ __launch_bounds__(256) void sconv1_t(const float* __restrict__ in,
                                                const float* __restrict__ w,
                                                float* __restrict__ h1) {
    int oy = blockIdx.x & 31;
    int b  = blockIdx.x >> 5;
    int t = threadIdx.x;
    int oc = t & 31;
    int oxg = t >> 5;

    __shared__ float in_s[3][3][64];
    __shared__ float w_s[27][32];

    int iy0 = oy * 2;
    for (int u = t; u < 576; u += 256) {
        int ix = u & 63;
        int ry = (u >> 6) % 3;
        int ic = u / 192;
        int iy = iy0 + ry;
        in_s[ic][ry][ix] = (iy < 64) ? in[((b * 3 + ic) * 64 + iy) * 64 + ix] : 0.f;
    }
    for (int u = t; u < 864; u += 256) {
        int oc2 = u & 31;
        int k = u >> 5;
        w_s[k][oc2] = w[oc2 * 27 + k];
    }
    __syncthreads();

    float acc[4] = {0.f, 0.f, 0.f, 0.f};
    #pragma unroll
    for (int ic = 0; ic < 3; ++ic) {
        #pragma unroll
        for (int ky = 0; ky < 3; ++ky) {
            float xv[9];
            #pragma unroll
            for (int i = 0; i < 9; ++i) {
                int ix = oxg * 8 + i;
                xv[i] = (ix < 64) ? in_s[ic][ky][ix] : 0.f;
            }
            #pragma unroll
            for (int kx = 0; kx < 3; ++kx) {
                float wv = w_s[ic * 9 + ky * 3 + kx][oc];
                #pragma unroll
                for (int p = 0; p < 4; ++p) acc[p] += wv * xv[2 * p + kx];
            }
        }
    }
    float* op = &h1[((b * 32 + oc) * 32 + oy) * 32 + oxg * 4];
    #pragma unroll
    for (int p = 0; p < 4; ++p) op[p] = fmaxf(acc[p], 0.f);
}

// ---------------- skim conv2 tiled fp32 (exact) fused relu+mean: [16,32,32,32] -> gsum2[16,64]
__global__ __launch_bounds__(256) void sconv2_t(const float* __restrict__ h1,
                                                const float* __restrict__ w,
                                                float* __restrict__ gsum2) {
    int oy = blockIdx.x;
    int ocg = blockIdx.y;
    int b = blockIdx.z;
    int t = threadIdx.x;
    int oc = t & 31;
    int oxg = t >> 5;

    __shared__ float in_s[32][3][32];
    __shared__ float w_s[288 * 32];   // [R=ic*9+k][oc ^ (R&31)]

    int iy0 = oy * 2;
    for (int u = t; u < 32 * 3 * 32; u += 256) {
        int ix = u & 31;
        int ry = (u >> 5) % 3;
        int ic = u / 96;
        int iy = iy0 + ry;
        in_s[ic][ry][ix] = (iy < 32) ? h1[((b * 32 + ic) * 32 + iy) * 32 + ix] : 0.f;
    }
    for (int u = t; u < 9216; u += 256) {
        int ocl = u / 288;
        int rem = u - ocl * 288;
        w_s[rem * 32 + (ocl ^ (rem & 31))] = w[(ocg * 32 + ocl) * 288 + rem];
    }
    __syncthreads();

    float acc0 = 0.f, acc1 = 0.f;
    for (int ic = 0; ic < 32; ++ic) {
        #pragma unroll
        for (int ky = 0; ky < 3; ++ky) {
            float xv[5];
            #pragma unroll
            for (int i = 0; i < 5; ++i) {
                int ix = oxg * 4 + i;
                xv[i] = (ix < 32) ? in_s[ic][ky][ix] : 0.f;
            }
            #pragma unroll
            for (int kx = 0; kx < 3; ++kx) {
                int R = ic * 9 + ky * 3 + kx;
                float wv = w_s[R * 32 + (oc ^ (R & 31))];
                acc0 += wv * xv[kx];
                acc1 += wv * xv[2 + kx];
            }
        }
    }
    float ps = fmaxf(acc0, 0.f) + fmaxf(acc1, 0.f);
    ps += __shfl_xor(ps, 32);
    if ((t & 32) == 0) atomicAdd(&gsum2[b * 64 + ocg * 32 + oc], ps);
}

// ---------------- eval gather + resize -> planar bf16, with INLINE policy/top-5
__global__ __launch_bounds__(256) void eval_resize_bf(const float* __restrict__ ff224,
                                                      const float* __restrict__ gsum2,
                                                      const float* __restrict__ pol_w,
                                                      const float* __restrict__ pol_b,
                                                      unsigned short* __restrict__ out) {
    int bid = blockIdx.x;
    int swz = (bid & 7) * 294 + (bid >> 3);
    int t = threadIdx.x;
    int gid = swz * 256 + t;
    int xg = gid % 56; int tmp = gid / 56;
    int oy = tmp % 224; tmp /= 224;
    int c = tmp % 3; int b = tmp / 3;   // constant per block (37632 % 256 == 0)

    __shared__ float fea[64];
    __shared__ float logits[TT];
    __shared__ int sidx[NSEL];

    if (t < 64) fea[t] = fmaxf(gsum2[b * 64 + t] * (1.f / 256.f), 0.f);
    __syncthreads();
    if (t < TT) {
        float l = pol_b[t];
        for (int cc = 0; cc < 64; ++cc) l += fea[cc] * pol_w[cc * TT + t];
        logits[t] = l;
    }
    __syncthreads();
    if (t == 0) {
        int sel[NSEL];
        bool used[TT];
        for (int i = 0; i < TT; ++i) used[i] = false;
        for (int k = 0; k < NSEL; ++k) {
            int best = 0; float bv = -1e30f; bool found = false;
            for (int i = 0; i < TT; ++i)
                if (!used[i] && (!found || logits[i] > bv)) { bv = logits[i]; best = i; found = true; }
            used[best] = true; sel[k] = best;
        }
        for (int a = 0; a < NSEL; ++a)
            for (int b2 = a + 1; b2 < NSEL; ++b2)
                if (sel[b2] < sel[a]) { int tmpv = sel[a]; sel[a] = sel[b2]; sel[b2] = tmpv; }
        for (int k = 0; k < NSEL; ++k) sidx[k] = sel[k];
    }
    __syncthreads();

    int ox0 = xg * 4;
    float sample = 5.f * (float)oy + 2.f;
    int jlo = max(0, 5 * oy - 3);
    int jhi = min(NSEL * 224 - 1, 5 * oy + 7);
    float ax = 0.f, ay = 0.f, az = 0.f, aw = 0.f, wsum = 0.f;
    for (int j = jlo; j <= jhi; ++j) {
        float w = fmaxf(0.f, 1.f - fabsf(sample - (float)j) * 0.2f);
        int s = j / 224, y = j % 224;
        int tf = sidx[s];
        const float4 v = *(const float4*)&ff224[((size_t)((b * TT + tf) * 3 + c) * 224 + y) * 224 + ox0];
        ax += w * v.x; ay += w * v.y; az += w * v.z; aw += w * v.w;
        wsum += w;
    }
    float inv = 1.f / wsum;
    ushort4 r;
    r.x = f2bf(ax * inv); r.y = f2bf(ay * inv); r.z = f2bf(az * inv); r.w = f2bf(aw * inv);
    *(ushort4*)&out[((size_t)((b * 3 + c) * 224 + oy)) * 224 + ox0] = r;
}

// ---------------- eval conv1 via MFMA: planar bf16 in -> channels-last bf16 [B,112,112,64]
__global__ __launch_bounds__(256) void conv1_mfma(const unsigned short* __restrict__ in,
                                                  const unsigned short* __restrict__ wpk1,
                                                  unsigned short* __restrict__ outcl) {
    int oxT = blockIdx.x;            // 0..6
    int oyT = blockIdx.y;            // 0..27
    int b = blockIdx.z;
    int t = threadIdx.x;
    int w = t >> 6;                  // wave -> oy = oyT*4 + w
    int lane = t & 63;
    int col = lane & 15;
    int kq = lane >> 4;

    __shared__ unsigned short in_s[3][9][36];

    int iy0 = oyT * 8, ix0 = oxT * 32;
    const unsigned short* ib = in + (size_t)b * 3 * 224 * 224;
    for (int i = t; i < 3 * 9 * 36; i += 256) {
        int rx = i % 36; int tmp = i / 36;
        int ry = tmp % 9; int ic = tmp / 9;
        int iy = iy0 + ry, ix = ix0 + rx;
        unsigned short v = 0;
        if (iy < 224 && ix < 224 && rx < 34) v = ib[((size_t)ic * 224 + iy) * 224 + ix];
        in_s[ic][ry][rx] = v;
    }
    __syncthreads();

    short8_t a[4];
    #pragma unroll
    for (int af = 0; af < 4; ++af)
        a[af] = *(const short8_t*)&wpk1[((af << 6) + lane) << 3];

    unsigned int bw[4];
    #pragma unroll
    for (int jj = 0; jj < 4; ++jj) {
        unsigned int lo = 0, hi = 0;
        int k0 = (kq << 3) + jj * 2;
        {
            int k = k0;
            if (k < 27) {
                int ic = k / 9, r9 = k - ic * 9;
                int ky = r9 / 3, kx = r9 - ky * 3;
                lo = in_s[ic][2 * w + ky][2 * col + kx];
            }
        }
        {
            int k = k0 + 1;
            if (k < 27) {
                int ic = k / 9, r9 = k - ic * 9;
                int ky = r9 / 3, kx = r9 - ky * 3;
                hi = in_s[ic][2 * w + ky][2 * col + kx];
            }
        }
        bw[jj] = lo | (hi << 16);
    }
    short8_t bv;
    {
        unsigned int* bvp = (unsigned int*)&bv;
        bvp[0] = bw[0]; bvp[1] = bw[1]; bvp[2] = bw[2]; bvp[3] = bw[3];
    }

    f32x4 acc[4];
    #pragma unroll
    for (int af = 0; af < 4; ++af) {
        acc[af] = (f32x4){0.f, 0.f, 0.f, 0.f};
        acc[af] = __builtin_amdgcn_mfma_f32_16x16x32_bf16(a[af], bv, acc[af], 0, 0, 0);
    }

    int oy = oyT * 4 + w;
    int ox = oxT * 16 + col;
    size_t pxb = ((size_t)((b * 112 + oy) * 112 + ox)) << 6;
    #pragma unroll
    for (int af = 0; af < 4; ++af) {
        unsigned int p0 = f2bf(fmaxf(acc[af][0], 0.f)) | ((unsigned int)f2bf(fmaxf(acc[af][1], 0.f)) << 16);
        unsigned int p1 = f2bf(fmaxf(acc[af][2], 0.f)) | ((unsigned int)f2bf(fmaxf(acc[af][3], 0.f)) << 16);
        uint2 pk; pk.x = p0; pk.y = p1;
        *(uint2*)&outcl[pxb + (af << 4) + (kq << 2)] = pk;
    }
}

// ---------------- eval conv2 via MFMA + LDS input, fused relu+mean -> gsum[B,128]
__global__ __launch_bounds__(256) void conv2_mfma(const unsigned short* __restrict__ g1cl,
                                                  const unsigned short* __restrict__ wpk,
                                                  float* __restrict__ gsum) {
    int oyT = blockIdx.x;            // 0..13 -> oy0 = oyT*4
    int oxT = blockIdx.y;            // 0..3  -> ox0 = oxT*16
    int b = blockIdx.z;
    int t = threadIdx.x;
    int wv = t >> 6;                 // 0..3 -> oc base wv*32
    int lane = t & 63;
    int col = lane & 15;
    int kq = lane >> 4;

    __shared__ unsigned short tile[9 * 34 * 64];

    int iy0 = oyT * 8, ix0 = oxT * 32;
    for (int u = t; u < 9 * 34 * 8; u += 256) {
        int cg = u & 7;
        int r = u >> 3;
        int rx = r % 34, ry = r / 34;
        int iy = iy0 + ry, ix = ix0 + rx;
        uint4 v = {0, 0, 0, 0};
        if (iy < 112 && ix < 112)
            v = *(const uint4*)&g1cl[(((size_t)((b * 112 + iy) * 112 + ix)) << 6) + (cg << 3)];
        int byte = ((r << 6) + (cg << 3)) << 1;
        byte ^= ((r >> 1) & 7) << 4;
        *(uint4*)((char*)tile + byte) = v;
    }
    __syncthreads();

    f32x4 acc[2][4];
    #pragma unroll
    for (int a = 0; a < 2; ++a)
        #pragma unroll
        for (int n = 0; n < 4; ++n)
            acc[a][n] = (f32x4){0.f, 0.f, 0.f, 0.f};

    #pragma unroll 1
    for (int tap = 0; tap < 9; ++tap) {
        const int ky = tap / 3;
        const int kx = tap - ky * 3;
        const int rxl = 2 * col + kx;
        #pragma unroll
        for (int h = 0; h < 2; ++h) {
            const unsigned short* wp = wpk + ((size_t)(((tap * 2 + h) * 8) + (wv << 1)) * 64 + lane) * 8;
            short8_t a0 = *(const short8_t*)wp;
            short8_t a1 = *(const short8_t*)(wp + 512);
            const int e = (h << 5) + (kq << 3);
            #pragma unroll
            for (int nf = 0; nf < 4; ++nf) {
                int r = (2 * nf + ky) * 34 + rxl;
                int byte = (((r << 6) + e) << 1) ^ (((r >> 1) & 7) << 4);
                short8_t bv = *(const short8_t*)((const char*)tile + byte);
                acc[0][nf] = __builtin_amdgcn_mfma_f32_16x16x32_bf16(a0, bv, acc[0][nf], 0, 0, 0);
                acc[1][nf] = __builtin_amdgcn_mfma_f32_16x16x32_bf16(a1, bv, acc[1][nf], 0, 0, 0);
            }
        }
    }

    #pragma unroll
    for (int a = 0; a < 2; ++a) {
        float s0 = 0.f, s1 = 0.f, s2 = 0.f, s3 = 0.f;
        #pragma unroll
        for (int nf = 0; nf < 4; ++nf) {
            s0 += fmaxf(acc[a][nf][0], 0.f);
            s1 += fmaxf(acc[a][nf][1], 0.f);
            s2 += fmaxf(acc[a][nf][2], 0.f);
            s3 += fmaxf(acc[a][nf][3], 0.f);
        }
        #pragma unroll
        for (int off = 1; off < 16; off <<= 1) {
            s0 += __shfl_xor(s0, off);
            s1 += __shfl_xor(s1, off);
            s2 += __shfl_xor(s2, off);
            s3 += __shfl_xor(s3, off);
        }
        if (col == 0) {
            int ocb = wv * 32 + a * 16 + kq * 4;
            atomicAdd(&gsum[b * 128 + ocb + 0], s0);
            atomicAdd(&gsum[b * 128 + ocb + 1], s1);
            atomicAdd(&gsum[b * 128 + ocb + 2], s2);
            atomicAdd(&gsum[b * 128 + ocb + 3], s3);
        }
    }
}

// ---------------- final FC: mean = gsum/3136 ; [B,128] @ [128,10] + b
__global__ void fc_kernel(const float* __restrict__ gsum, const float* __restrict__ fcw,
                          const float* __restrict__ fcb, float* __restrict__ out) {
    int gid = blockIdx.x * blockDim.x + threadIdx.x;
    if (gid >= BB * NCLS) return;
    int cls = gid % NCLS, b = gid / NCLS;
    float s = 0.f;
    for (int c = 0; c < 128; ++c) s += gsum[b * 128 + c] * fcw[c * NCLS + cls];
    out[gid] = fcb[cls] + s * (1.f / 3136.f);
}

extern "C" void kernel_launch(void* const* d_in, const int* in_sizes, int n_in,
                              void* d_out, int out_size, void* d_ws, size_t ws_size,
                              hipStream_t stream) {
    const float* ff64  = (const float*)d_in[0];
    const float* ff224 = (const float*)d_in[1];
    const float* sw1   = (const float*)d_in[2];
    const float* sw2   = (const float*)d_in[3];
    const float* polw  = (const float*)d_in[4];
    const float* polb  = (const float*)d_in[5];
    const float* ew1   = (const float*)d_in[6];
    const float* ew2   = (const float*)d_in[7];
    const float* fcw   = (const float*)d_in[8];
    const float* fcb   = (const float*)d_in[9];
    float* out = (float*)d_out;

    float* ws = (float*)d_ws;
    float* skim_res = ws;                       // 196608 f
    float* h1 = skim_res + 196608;              // 524288 f
    float* gsum2 = h1 + 524288;                 // 1024 f
    float* gsum = gsum2 + 1024;                 // 2048 f
    unsigned short* eval_bf = (unsigned short*)(gsum + 2048);  // 2408448 bf16
    unsigned short* g1cl = eval_bf + 2408448;   // 12845056 bf16
    unsigned short* wpk  = g1cl + 12845056;     // 73728 bf16
    unsigned short* wpk1 = wpk + 73728;         // 2048 bf16

    // 1. skim resize (scalar, 768 blocks for TLP) + weight pack + zero accumulators
    prep_all<<<1056, 256, 0, stream>>>(ff64, ew2, ew1, skim_res, wpk, wpk1, gsum, gsum2);

    // 2-3. skim convs (exact fp32)
    sconv1_t<<<512, 256, 0, stream>>>(skim_res, sw1, h1);
    sconv2_t<<<dim3(16, 2, BB), 256, 0, stream>>>(h1, sw2, gsum2);

    // 4. gather + resize -> bf16 (inline policy/top-5 per block; XCD-chunked swizzle)
    eval_resize_bf<<<2352, 256, 0, stream>>>(ff224, gsum2, polw, polb, eval_bf);

    // 5. eval conv1 (MFMA)
    conv1_mfma<<<dim3(7, 28, BB), 256, 0, stream>>>(eval_bf, wpk1, g1cl);

    // 6. eval conv2 (MFMA) + fused relu/mean
    conv2_mfma<<<dim3(14, 4, BB), 256, 0, stream>>>(g1cl, wpk, gsum);

    // 7. final FC
    fc_kernel<<<1, 256, 0, stream>>>(gsum, fcw, fcb, out);
}

// Round 15
// 104.866 us; speedup vs baseline: 1.1422x; 1.1422x over previous
//
#include <hip/hip_runtime.h>

#define BB 16
#define TT 30
#define NSEL 5
#define NCLS 10

typedef __attribute__((ext_vector_type(8))) short short8_t;
typedef __attribute__((ext_vector_type(4))) float f32x4;

__device__ inline unsigned short f2bf(float x) {
    unsigned int u = __float_as_uint(x);
    unsigned int r = u + 0x7FFFu + ((u >> 16) & 1u);
    return (unsigned short)(r >> 16);
}

// ---------------- prep_all: blocks 0..191 skim resize (float4); 192..479 weight pack + zeroing
__global__ __launch_bounds__(256) void prep_all(const float* __restrict__ ff64,
                                                const float* __restrict__ w2,
                                                const float* __restrict__ w1,
                                                float* __restrict__ skim_res,
                                                unsigned short* __restrict__ wpk,
                                                unsigned short* __restrict__ wpk1,
                                                float* __restrict__ gsum,
                                                float* __restrict__ gsum2) {
    int bid = blockIdx.x;
    int t = threadIdx.x;
    if (bid < 192) {
        int gid = bid * 256 + t;
        int xg = gid & 15;
        int oy = (gid >> 4) & 63;
        int bc = gid >> 10;
        int c = bc % 3, b = bc / 3;
        int ox0 = xg * 4;
        float sample = 30.f * (float)oy + 14.5f;
        int jlo = max(0, 30 * oy - 16);
        int jhi = min(TT * 64 - 1, 30 * oy + 45);
        float ax = 0.f, ay = 0.f, az = 0.f, aw = 0.f, ws = 0.f;
        for (int j = jlo; j <= jhi; ++j) {
            float w = fmaxf(0.f, 1.f - fabsf(sample - (float)j) * (1.f / 30.f));
            int tt = j >> 6, y = j & 63;
            const float4 v = *(const float4*)&ff64[(((b * TT + tt) * 3 + c) << 12) + (y << 6) + ox0];
            ax += w * v.x; ay += w * v.y; az += w * v.z; aw += w * v.w;
            ws += w;
        }
        float inv = 1.f / ws;
        float4 r; r.x = ax * inv; r.y = ay * inv; r.z = az * inv; r.w = aw * inv;
        *(float4*)&skim_res[(((b * 3 + c) << 6) + oy) * 64 + ox0] = r;
    } else {
        int i = (bid - 192) * 256 + t;
        if (i < BB * 128) gsum[i] = 0.f;
        if (i < BB * 64) gsum2[i] = 0.f;
        if (i < 4 * 64 * 8) {
            int j = i & 7;
            int lane = (i >> 3) & 63;
            int af = i >> 9;
            int oc = af * 16 + (lane & 15);
            int k = ((lane >> 4) << 3) + j;
            wpk1[i] = (k < 27) ? f2bf(w1[oc * 27 + k]) : (unsigned short)0;
        }
        if (i < 9 * 2 * 8 * 64 * 8) {
            int j = i & 7;
            int lane = (i >> 3) & 63;
            int af = (i >> 9) & 7;
            int h = (i >> 12) & 1;
            int tap = i >> 13;
            int oc = af * 16 + (lane & 15);
            int ic = h * 32 + ((lane >> 4) << 3) + j;
            int ky = tap / 3, kx = tap % 3;
            wpk[i] = f2bf(w2[((size_t)(oc * 64 + ic)) * 9 + ky * 3 + kx]);
        }
    }
}

// ---------------- skim conv1 tiled fp32 (exact): [16,3,64,64] -> [16,32,32,32]
__global__ __launch_bounds__(256) void sconv1_t(const float* __restrict__ in,
                                                const float* __restrict__ w,
                                                float* __restrict__ h1) {
    int oy = blockIdx.x & 31;
    int b  = blockIdx.x >> 5;
    int t = threadIdx.x;
    int oc = t & 31;
    int oxg = t >> 5;

    __shared__ float in_s[3][3][64];
    __shared__ float w_s[27][32];

    int iy0 = oy * 2;
    for (int u = t; u < 576; u += 256) {
        int ix = u & 63;
        int ry = (u >> 6) % 3;
        int ic = u / 192;
        int iy = iy0 + ry;
        in_s[ic][ry][ix] = (iy < 64) ? in[((b * 3 + ic) * 64 + iy) * 64 + ix] : 0.f;
    }
    for (int u = t; u < 864; u += 256) {
        int oc2 = u & 31;
        int k = u >> 5;
        w_s[k][oc2] = w[oc2 * 27 + k];
    }
    __syncthreads();

    float acc[4] = {0.f, 0.f, 0.f, 0.f};
    #pragma unroll
    for (int ic = 0; ic < 3; ++ic) {
        #pragma unroll
        for (int ky = 0; ky < 3; ++ky) {
            float xv[9];
            #pragma unroll
            for (int i = 0; i < 9; ++i) {
                int ix = oxg * 8 + i;
                xv[i] = (ix < 64) ? in_s[ic][ky][ix] : 0.f;
            }
            #pragma unroll
            for (int kx = 0; kx < 3; ++kx) {
                float wv = w_s[ic * 9 + ky * 3 + kx][oc];
                #pragma unroll
                for (int p = 0; p < 4; ++p) acc[p] += wv * xv[2 * p + kx];
            }
        }
    }
    float* op = &h1[((b * 32 + oc) * 32 + oy) * 32 + oxg * 4];
    #pragma unroll
    for (int p = 0; p < 4; ++p) op[p] = fmaxf(acc[p], 0.f);
}

// ---------------- skim conv2 tiled fp32 (exact) fused relu+mean: [16,32,32,32] -> gsum2[16,64]
__global__ __launch_bounds__(256) void sconv2_t(const float* __restrict__ h1,
                                                const float* __restrict__ w,
                                                float* __restrict__ gsum2) {
    int oy = blockIdx.x;
    int ocg = blockIdx.y;
    int b = blockIdx.z;
    int t = threadIdx.x;
    int oc = t & 31;
    int oxg = t >> 5;

    __shared__ float in_s[32][3][32];
    __shared__ float w_s[288 * 32];   // [R=ic*9+k][oc ^ (R&31)]

    int iy0 = oy * 2;
    for (int u = t; u < 32 * 3 * 32; u += 256) {
        int ix = u & 31;
        int ry = (u >> 5) % 3;
        int ic = u / 96;
        int iy = iy0 + ry;
        in_s[ic][ry][ix] = (iy < 32) ? h1[((b * 32 + ic) * 32 + iy) * 32 + ix] : 0.f;
    }
    for (int u = t; u < 9216; u += 256) {
        int ocl = u / 288;
        int rem = u - ocl * 288;
        w_s[rem * 32 + (ocl ^ (rem & 31))] = w[(ocg * 32 + ocl) * 288 + rem];
    }
    __syncthreads();

    float acc0 = 0.f, acc1 = 0.f;
    for (int ic = 0; ic < 32; ++ic) {
        #pragma unroll
        for (int ky = 0; ky < 3; ++ky) {
            float xv[5];
            #pragma unroll
            for (int i = 0; i < 5; ++i) {
                int ix = oxg * 4 + i;
                xv[i] = (ix < 32) ? in_s[ic][ky][ix] : 0.f;
            }
            #pragma unroll
            for (int kx = 0; kx < 3; ++kx) {
                int R = ic * 9 + ky * 3 + kx;
                float wv = w_s[R * 32 + (oc ^ (R & 31))];
                acc0 += wv * xv[kx];
                acc1 += wv * xv[2 + kx];
            }
        }
    }
    float ps = fmaxf(acc0, 0.f) + fmaxf(acc1, 0.f);
    ps += __shfl_xor(ps, 32);
    if ((t & 32) == 0) atomicAdd(&gsum2[b * 64 + ocg * 32 + oc], ps);
}

// ---------------- eval conv1 FUSED: policy/top-5 + gather-resize staging + MFMA
// in: ff224 fp32 + gsum2 ; out: channels-last bf16 [B,112,112,64]
__global__ __launch_bounds__(256) void conv1_fused(const float* __restrict__ ff224,
                                                   const float* __restrict__ gsum2,
                                                   const float* __restrict__ pol_w,
                                                   const float* __restrict__ pol_b,
                                                   const unsigned short* __restrict__ wpk1,
                                                   unsigned short* __restrict__ outcl) {
    int oxT = blockIdx.x;            // 0..6
    int oyT = blockIdx.y;            // 0..27
    int b = blockIdx.z;
    int t = threadIdx.x;
    int w = t >> 6;                  // wave -> oy = oyT*4 + w
    int lane = t & 63;
    int col = lane & 15;
    int kq = lane >> 4;

    __shared__ float fea[64];
    __shared__ float logits[TT];
    __shared__ unsigned char insel[TT];
    __shared__ int sidx[NSEL];
    __shared__ unsigned short in_s[3][9][36];

    // --- policy + parallel-rank top-5 (exact jax top_k semantics: ties -> lower idx)
    if (t < 64) fea[t] = fmaxf(gsum2[b * 64 + t] * (1.f / 256.f), 0.f);
    __syncthreads();
    if (t < TT) {
        float l = pol_b[t];
        for (int cc = 0; cc < 64; ++cc) l += fea[cc] * pol_w[cc * TT + t];
        logits[t] = l;
    }
    __syncthreads();
    if (t < TT) {
        float li = logits[t];
        int rank = 0;
        for (int j = 0; j < TT; ++j) {
            float lj = logits[j];
            rank += (lj > li) || (lj == li && j < t);
        }
        insel[t] = (rank < NSEL) ? 1 : 0;
    }
    __syncthreads();
    if (t < TT && insel[t]) {
        int pos = 0;
        for (int j = 0; j < t; ++j) pos += insel[j];
        sidx[pos] = t;
    }
    __syncthreads();

    // --- gather + resize staging: 243 float4 items (4 px each), 11 fixed taps
    int iy0 = oyT * 8, ix0 = oxT * 32;
    if (t < 243) {
        int rx0 = (t % 9) * 4;
        int ry = (t / 9) % 9;
        int ic = t / 81;
        int oy = iy0 + ry;
        int ox0 = ix0 + rx0;
        ushort4 v4 = {0, 0, 0, 0};
        if (oy < 224 && ox0 < 224) {
            float sample = 5.f * (float)oy + 2.f;
            int j0 = 5 * oy - 3;
            float ax = 0.f, ay = 0.f, az = 0.f, aw = 0.f, wsum = 0.f;
            #pragma unroll
            for (int dj = 0; dj < 11; ++dj) {
                int j = j0 + dj;
                float wt = (j >= 0 && j < NSEL * 224)
                               ? fmaxf(0.f, 1.f - fabsf(sample - (float)j) * 0.2f) : 0.f;
                int jc = min(max(j, 0), NSEL * 224 - 1);
                int s = jc / 224, y = jc % 224;
                int tf = sidx[s];
                const float4 v = *(const float4*)&ff224[((size_t)((b * TT + tf) * 3 + ic) * 224 + y) * 224 + ox0];
                ax += wt * v.x; ay += wt * v.y; az += wt * v.z; aw += wt * v.w;
                wsum += wt;
            }
            float inv = 1.f / wsum;
            v4.x = f2bf(ax * inv); v4.y = f2bf(ay * inv);
            v4.z = f2bf(az * inv); v4.w = f2bf(aw * inv);
        }
        *(ushort4*)&in_s[ic][ry][rx0] = v4;
    }
    __syncthreads();

    // --- conv1 MFMA (unchanged)
    short8_t a[4];
    #pragma unroll
    for (int af = 0; af < 4; ++af)
        a[af] = *(const short8_t*)&wpk1[((af << 6) + lane) << 3];

    unsigned int bw[4];
    #pragma unroll
    for (int jj = 0; jj < 4; ++jj) {
        unsigned int lo = 0, hi = 0;
        int k0 = (kq << 3) + jj * 2;
        {
            int k = k0;
            if (k < 27) {
                int ic = k / 9, r9 = k - ic * 9;
                int ky = r9 / 3, kx = r9 - ky * 3;
                lo = in_s[ic][2 * w + ky][2 * col + kx];
            }
        }
        {
            int k = k0 + 1;
            if (k < 27) {
                int ic = k / 9, r9 = k - ic * 9;
                int ky = r9 / 3, kx = r9 - ky * 3;
                hi = in_s[ic][2 * w + ky][2 * col + kx];
            }
        }
        bw[jj] = lo | (hi << 16);
    }
    short8_t bv;
    {
        unsigned int* bvp = (unsigned int*)&bv;
        bvp[0] = bw[0]; bvp[1] = bw[1]; bvp[2] = bw[2]; bvp[3] = bw[3];
    }

    f32x4 acc[4];
    #pragma unroll
    for (int af = 0; af < 4; ++af) {
        acc[af] = (f32x4){0.f, 0.f, 0.f, 0.f};
        acc[af] = __builtin_amdgcn_mfma_f32_16x16x32_bf16(a[af], bv, acc[af], 0, 0, 0);
    }

    int oy = oyT * 4 + w;
    int ox = oxT * 16 + col;
    size_t pxb = ((size_t)((b * 112 + oy) * 112 + ox)) << 6;
    #pragma unroll
    for (int af = 0; af < 4; ++af) {
        unsigned int p0 = f2bf(fmaxf(acc[af][0], 0.f)) | ((unsigned int)f2bf(fmaxf(acc[af][1], 0.f)) << 16);
        unsigned int p1 = f2bf(fmaxf(acc[af][2], 0.f)) | ((unsigned int)f2bf(fmaxf(acc[af][3], 0.f)) << 16);
        uint2 pk; pk.x = p0; pk.y = p1;
        *(uint2*)&outcl[pxb + (af << 4) + (kq << 2)] = pk;
    }
}

// ---------------- eval conv2 via MFMA + LDS input, fused relu+mean -> gsum[B,128]
__global__ __launch_bounds__(256) void conv2_mfma(const unsigned short* __restrict__ g1cl,
                                                  const unsigned short* __restrict__ wpk,
                                                  float* __restrict__ gsum) {
    int oyT = blockIdx.x;            // 0..13 -> oy0 = oyT*4
    int oxT = blockIdx.y;            // 0..3  -> ox0 = oxT*16
    int b = blockIdx.z;
    int t = threadIdx.x;
    int wv = t >> 6;                 // 0..3 -> oc base wv*32
    int lane = t & 63;
    int col = lane & 15;
    int kq = lane >> 4;

    __shared__ unsigned short tile[9 * 34 * 64];

    int iy0 = oyT * 8, ix0 = oxT * 32;
    for (int u = t; u < 9 * 34 * 8; u += 256) {
        int cg = u & 7;
        int r = u >> 3;
        int rx = r % 34, ry = r / 34;
        int iy = iy0 + ry, ix = ix0 + rx;
        uint4 v = {0, 0, 0, 0};
        if (iy < 112 && ix < 112)
            v = *(const uint4*)&g1cl[(((size_t)((b * 112 + iy) * 112 + ix)) << 6) + (cg << 3)];
        int byte = ((r << 6) + (cg << 3)) << 1;
        byte ^= ((r >> 1) & 7) << 4;
        *(uint4*)((char*)tile + byte) = v;
    }
    __syncthreads();

    f32x4 acc[2][4];
    #pragma unroll
    for (int a = 0; a < 2; ++a)
        #pragma unroll
        for (int n = 0; n < 4; ++n)
            acc[a][n] = (f32x4){0.f, 0.f, 0.f, 0.f};

    #pragma unroll 1
    for (int tap = 0; tap < 9; ++tap) {
        const int ky = tap / 3;
        const int kx = tap - ky * 3;
        const int rxl = 2 * col + kx;
        #pragma unroll
        for (int h = 0; h < 2; ++h) {
            const unsigned short* wp = wpk + ((size_t)(((tap * 2 + h) * 8) + (wv << 1)) * 64 + lane) * 8;
            short8_t a0 = *(const short8_t*)wp;
            short8_t a1 = *(const short8_t*)(wp + 512);
            const int e = (h << 5) + (kq << 3);
            #pragma unroll
            for (int nf = 0; nf < 4; ++nf) {
                int r = (2 * nf + ky) * 34 + rxl;
                int byte = (((r << 6) + e) << 1) ^ (((r >> 1) & 7) << 4);
                short8_t bv = *(const short8_t*)((const char*)tile + byte);
                acc[0][nf] = __builtin_amdgcn_mfma_f32_16x16x32_bf16(a0, bv, acc[0][nf], 0, 0, 0);
                acc[1][nf] = __builtin_amdgcn_mfma_f32_16x16x32_bf16(a1, bv, acc[1][nf], 0, 0, 0);
            }
        }
    }

    #pragma unroll
    for (int a = 0; a < 2; ++a) {
        float s0 = 0.f, s1 = 0.f, s2 = 0.f, s3 = 0.f;
        #pragma unroll
        for (int nf = 0; nf < 4; ++nf) {
            s0 += fmaxf(acc[a][nf][0], 0.f);
            s1 += fmaxf(acc[a][nf][1], 0.f);
            s2 += fmaxf(acc[a][nf][2], 0.f);
            s3 += fmaxf(acc[a][nf][3], 0.f);
        }
        #pragma unroll
        for (int off = 1; off < 16; off <<= 1) {
            s0 += __shfl_xor(s0, off);
            s1 += __shfl_xor(s1, off);
            s2 += __shfl_xor(s2, off);
            s3 += __shfl_xor(s3, off);
        }
        if (col == 0) {
            int ocb = wv * 32 + a * 16 + kq * 4;
            atomicAdd(&gsum[b * 128 + ocb + 0], s0);
            atomicAdd(&gsum[b * 128 + ocb + 1], s1);
            atomicAdd(&gsum[b * 128 + ocb + 2], s2);
            atomicAdd(&gsum[b * 128 + ocb + 3], s3);
        }
    }
}

// ---------------- final FC: mean = gsum/3136 ; [B,128] @ [128,10] + b
__global__ void fc_kernel(const float* __restrict__ gsum, const float* __restrict__ fcw,
                          const float* __restrict__ fcb, float* __restrict__ out) {
    int gid = blockIdx.x * blockDim.x + threadIdx.x;
    if (gid >= BB * NCLS) return;
    int cls = gid % NCLS, b = gid / NCLS;
    float s = 0.f;
    for (int c = 0; c < 128; ++c) s += gsum[b * 128 + c] * fcw[c * NCLS + cls];
    out[gid] = fcb[cls] + s * (1.f / 3136.f);
}

extern "C" void kernel_launch(void* const* d_in, const int* in_sizes, int n_in,
                              void* d_out, int out_size, void* d_ws, size_t ws_size,
                              hipStream_t stream) {
    const float* ff64  = (const float*)d_in[0];
    const float* ff224 = (const float*)d_in[1];
    const float* sw1   = (const float*)d_in[2];
    const float* sw2   = (const float*)d_in[3];
    const float* polw  = (const float*)d_in[4];
    const float* polb  = (const float*)d_in[5];
    const float* ew1   = (const float*)d_in[6];
    const float* ew2   = (const float*)d_in[7];
    const float* fcw   = (const float*)d_in[8];
    const float* fcb   = (const float*)d_in[9];
    float* out = (float*)d_out;

    float* ws = (float*)d_ws;
    float* skim_res = ws;                       // 196608 f
    float* h1 = skim_res + 196608;              // 524288 f
    float* gsum2 = h1 + 524288;                 // 1024 f
    float* gsum = gsum2 + 1024;                 // 2048 f
    unsigned short* g1cl = (unsigned short*)(gsum + 2048);  // 12845056 bf16
    unsigned short* wpk  = g1cl + 12845056;     // 73728 bf16
    unsigned short* wpk1 = wpk + 73728;         // 2048 bf16

    // 1. skim resize (float4) + weight pack + zero accumulators
    prep_all<<<480, 256, 0, stream>>>(ff64, ew2, ew1, skim_res, wpk, wpk1, gsum, gsum2);

    // 2-3. skim convs (exact fp32)
    sconv1_t<<<512, 256, 0, stream>>>(skim_res, sw1, h1);
    sconv2_t<<<dim3(16, 2, BB), 256, 0, stream>>>(h1, sw2, gsum2);

    // 4. eval conv1 FUSED: policy/top-5 + gather-resize + MFMA (eval_resize kernel removed)
    conv1_fused<<<dim3(7, 28, BB), 256, 0, stream>>>(ff224, gsum2, polw, polb, wpk1, g1cl);

    // 5. eval conv2 (MFMA) + fused relu/mean
    conv2_mfma<<<dim3(14, 4, BB), 256, 0, stream>>>(g1cl, wpk, gsum);

    // 6. final FC
    fc_kernel<<<1, 256, 0, stream>>>(gsum, fcw, fcb, out);
}